// Round 13
// baseline (217.244 us; speedup 1.0000x reference)
//
#include <hip/hip_runtime.h>
#include <hip/hip_cooperative_groups.h>

namespace cg = cooperative_groups;

#define NN 4096
#define DD 2048
#define MARGIN_F 0.3f
#define NTILES 1056  // 64x128 tiles covering the upper triangle (dupes OK)
#define BK 256       // K bytes per stage
#define NIT (DD / BK)  // 8
#define QS (127.0f / 6.0f)
#define C2 (2.0f * (6.0f / 127.0f) * (6.0f / 127.0f))  // 2/QS^2

typedef __attribute__((ext_vector_type(4))) int i32x4;

__device__ __forceinline__ unsigned q8(float v) {
    int i = __float2int_rn(v * QS);
    i = min(127, max(-127, i));
    return (unsigned)(i & 255);
}

// ---------------------------------------------------------------------------
// R13 = R12 with the attribute-name typo fixed. Single cooperative persistent
// kernel: prep (all waves) -> grid.sync -> persistent tile loop (R9 gemm
// verbatim; tid += G preserves the super-block XCD partition since G%8==0)
// -> grid.sync -> block 0 finalize. Grid = occupancy-query blocks/CU * CUs
// (deadlock-proof), fallback to the proven R9 two-kernel path if the
// cooperative launch fails.
// ---------------------------------------------------------------------------

__global__ __launch_bounds__(256) void fused_kernel(
    const float* __restrict__ x,
    const int* __restrict__ labels,
    unsigned char* __restrict__ xq,
    float* __restrict__ sq,
    unsigned int* __restrict__ ap,
    unsigned int* __restrict__ an,
    float* __restrict__ out) {
    __shared__ __align__(16) unsigned char As[64 * BK];    // 16 KB
    __shared__ __align__(16) unsigned char Bs[128 * BK];   // 32 KB

    const int t = threadIdx.x;
    const int lane = t & 63;
    const int wave = t >> 6;
    const int G = gridDim.x;

    // ---- phase 1: prep (quantize rows, sums of squares, init ap/an) ----
    for (int row = blockIdx.x * 4 + wave; row < NN; row += G * 4) {
        const float* xr = x + (size_t)row * DD;
        unsigned int* orow = (unsigned int*)(xq + (size_t)row * DD);
        float s = 0.0f;
#pragma unroll
        for (int j = 0; j < 8; ++j) {
            float4 v = ((const float4*)xr)[j * 64 + lane];
            s += v.x * v.x + v.y * v.y + v.z * v.z + v.w * v.w;
            orow[j * 64 + lane] =
                q8(v.x) | (q8(v.y) << 8) | (q8(v.z) << 16) | (q8(v.w) << 24);
        }
        for (int off = 32; off > 0; off >>= 1) s += __shfl_down(s, off, 64);
        if (lane == 0) {
            sq[row] = s;
            ap[row] = 0u;            // hardest-positive max starts at 0
            an[row] = 0x7F800000u;   // +inf
        }
    }
    cg::this_grid().sync();

    // ---- phase 2: persistent GEMM tile loop (R9 structure verbatim) ----
    const int c = lane & 15;   // fragment column lane
    const int q = lane >> 4;   // k-quad
    const int wc = wave * 32;  // wave col offset
    const int rowb = t >> 4;
    const int colsw = (t & 15) ^ (rowb & 15);
    const int phase = blockIdx.x & (NIT - 1);  // K-start stagger

    for (int tid = blockIdx.x; tid < NTILES; tid += G) {
        // super-block decode (bijective over 1056): XCD tid&7 owns
        // contiguous run [132x, 132x+132); (tid+G)&7 == tid&7 since G%8==0.
        int g = (tid & 7) * (NTILES / 8) + (tid >> 3);
        int si = 0, row_cnt = 244;
        while (g >= row_cnt) { g -= row_cnt; ++si; row_cnt -= 32; }
        int mi64, nj;
        if (g < 20) {  // diagonal super: 8 row-tiles x 4 col-tiles triangle
            int ml = 0;
            while (g >= 4 - (ml >> 1)) { g -= 4 - (ml >> 1); ++ml; }
            mi64 = si * 8 + ml;
            nj = si * 4 + (ml >> 1) + g;
        } else {       // off-diagonal super: full 8x4
            g -= 20;
            const int sj = si + 1 + (g >> 5);
            const int r = g & 31;
            mi64 = si * 8 + (r >> 2);
            nj = sj * 4 + (r & 3);
        }
        const int row0 = mi64 * 64;
        const int col0 = nj * 128;

        i32x4 acc[4][2];
#pragma unroll
        for (int mi = 0; mi < 4; ++mi)
#pragma unroll
            for (int ni = 0; ni < 2; ++ni)
                acc[mi][ni] = (i32x4){0, 0, 0, 0};

        const unsigned char* gA[4];
        const unsigned char* gB[8];
#pragma unroll
        for (int s = 0; s < 4; ++s)
            gA[s] = xq + (size_t)(row0 + rowb + 16 * s) * DD + colsw * 16;
#pragma unroll
        for (int s = 0; s < 8; ++s)
            gB[s] = xq + (size_t)(col0 + rowb + 16 * s) * DD + colsw * 16;

        for (int it = 0; it < NIT; ++it) {
            const int k0 = ((it + phase) & (NIT - 1)) * BK;
#pragma unroll
            for (int s = 0; s < 4; ++s)
                __builtin_amdgcn_global_load_lds(
                    (const __attribute__((address_space(1))) void*)(gA[s] + k0),
                    (__attribute__((address_space(3))) void*)&As[(t + 256 * s) * 16],
                    16, 0, 0);
#pragma unroll
            for (int s = 0; s < 8; ++s)
                __builtin_amdgcn_global_load_lds(
                    (const __attribute__((address_space(1))) void*)(gB[s] + k0),
                    (__attribute__((address_space(3))) void*)&Bs[(t + 256 * s) * 16],
                    16, 0, 0);
            __syncthreads();

            const i32x4* Av = (const i32x4*)As;
            const i32x4* Bv = (const i32x4*)Bs;
#pragma unroll
            for (int ks = 0; ks < 4; ++ks) {
                const int kc = q + 4 * ks;
                i32x4 af[4], bfr[2];
#pragma unroll
                for (int mi = 0; mi < 4; ++mi) {
                    const int r = mi * 16 + c;
                    af[mi] = Av[r * 16 + (kc ^ (r & 15))];
                }
#pragma unroll
                for (int ni = 0; ni < 2; ++ni) {
                    const int r = wc + ni * 16 + c;
                    bfr[ni] = Bv[r * 16 + (kc ^ (r & 15))];
                }
#pragma unroll
                for (int mi = 0; mi < 4; ++mi)
#pragma unroll
                    for (int ni = 0; ni < 2; ++ni)
                        acc[mi][ni] = __builtin_amdgcn_mfma_i32_16x16x64_i8(
                            af[mi], bfr[ni], acc[mi][ni], 0, 0, 0);
            }
            __syncthreads();
        }

        // --- epilogue (LDS-free; safe against next tile's staging) ---
        float sq_col[2];
        int lab_col[2];
#pragma unroll
        for (int ni = 0; ni < 2; ++ni) {
            const int gj = col0 + wc + ni * 16 + c;
            sq_col[ni] = sq[gj];
            lab_col[ni] = labels[gj];
        }
        int lab_row[4][4];
        float dist[4][2][4];
#pragma unroll
        for (int mi = 0; mi < 4; ++mi) {
#pragma unroll
            for (int r = 0; r < 4; ++r) {
                const int gi = row0 + mi * 16 + q * 4 + r;
                const float sqi = sq[gi];
                lab_row[mi][r] = labels[gi];
#pragma unroll
                for (int ni = 0; ni < 2; ++ni) {
                    float d2 = sqi + sq_col[ni] - C2 * (float)acc[mi][ni][r];
                    dist[mi][ni][r] = sqrtf(fmaxf(d2, 0.0f));
                }
            }
        }
        // row-side
#pragma unroll
        for (int mi = 0; mi < 4; ++mi) {
#pragma unroll
            for (int r = 0; r < 4; ++r) {
                const int gi = row0 + mi * 16 + q * 4 + r;
                const int li = lab_row[mi][r];
                float apm = 0.0f;
                float anm = __builtin_inff();
#pragma unroll
                for (int ni = 0; ni < 2; ++ni) {
                    const int gj = col0 + wc + ni * 16 + c;
                    const float d = dist[mi][ni][r];
                    if (li == lab_col[ni]) {
                        if (gi != gj) apm = fmaxf(apm, d);
                    } else {
                        anm = fminf(anm, d);
                    }
                }
#pragma unroll
                for (int off = 1; off < 16; off <<= 1) {
                    apm = fmaxf(apm, __shfl_xor(apm, off, 16));
                    anm = fminf(anm, __shfl_xor(anm, off, 16));
                }
                if (c == 0) {
                    atomicMax(&ap[gi], __float_as_uint(apm));
                    atomicMin(&an[gi], __float_as_uint(anm));
                }
            }
        }
        // column-side (transposed)
#pragma unroll
        for (int ni = 0; ni < 2; ++ni) {
            const int gj = col0 + wc + ni * 16 + c;
            const int lj = lab_col[ni];
            float apm = 0.0f;
            float anm = __builtin_inff();
#pragma unroll
            for (int mi = 0; mi < 4; ++mi) {
#pragma unroll
                for (int r = 0; r < 4; ++r) {
                    const int gi = row0 + mi * 16 + q * 4 + r;
                    const float d = dist[mi][ni][r];
                    if (lj == lab_row[mi][r]) {
                        if (gi != gj) apm = fmaxf(apm, d);
                    } else {
                        anm = fminf(anm, d);
                    }
                }
            }
            apm = fmaxf(apm, __shfl_xor(apm, 16, 64));
            anm = fminf(anm, __shfl_xor(anm, 16, 64));
            apm = fmaxf(apm, __shfl_xor(apm, 32, 64));
            anm = fminf(anm, __shfl_xor(anm, 32, 64));
            if (q == 0) {
                atomicMax(&ap[gj], __float_as_uint(apm));
                atomicMin(&an[gj], __float_as_uint(anm));
            }
        }
    }

    cg::this_grid().sync();

    // ---- phase 3: finalize (block 0) ----
    if (blockIdx.x == 0) {
        float sum = 0.0f;
        int cnt = 0;
        for (int i = t; i < NN; i += 256) {
            const float a = __uint_as_float(__hip_atomic_load(
                &ap[i], __ATOMIC_RELAXED, __HIP_MEMORY_SCOPE_AGENT));
            const float b = __uint_as_float(__hip_atomic_load(
                &an[i], __ATOMIC_RELAXED, __HIP_MEMORY_SCOPE_AGENT));
            if ((a > 0.0f) && (b < __builtin_inff())) {
                sum += fmaxf(a - b + MARGIN_F, 0.0f);
                cnt += 1;
            }
        }
        for (int off = 32; off > 0; off >>= 1) {
            sum += __shfl_down(sum, off, 64);
            cnt += __shfl_down(cnt, off, 64);
        }
        float* ssum = (float*)Bs;
        int* scnt = (int*)Bs + 8;
        if (lane == 0) { ssum[wave] = sum; scnt[wave] = cnt; }
        __syncthreads();
        if (t == 0) {
            float s = 0.0f; int n = 0;
#pragma unroll
            for (int w = 0; w < 4; ++w) { s += ssum[w]; n += scnt[w]; }
            out[0] = (n > 0) ? s / (float)n : 0.0f;
        }
    }
}

// ---------------- fallback path: R9 two-kernel version (proven 64 us) ------

__global__ __launch_bounds__(256) void prep_kernel(const float* __restrict__ x,
                                                   unsigned char* __restrict__ xq,
                                                   float* __restrict__ sq,
                                                   unsigned int* __restrict__ ap,
                                                   unsigned int* __restrict__ an,
                                                   int* __restrict__ counter) {
    const int wave = threadIdx.x >> 6, lane = threadIdx.x & 63;
    const int row = blockIdx.x * 4 + wave;
    const float* xr = x + (size_t)row * DD;
    unsigned int* orow = (unsigned int*)(xq + (size_t)row * DD);
    float s = 0.0f;
#pragma unroll
    for (int j = 0; j < 8; ++j) {
        float4 v = ((const float4*)xr)[j * 64 + lane];
        s += v.x * v.x + v.y * v.y + v.z * v.z + v.w * v.w;
        orow[j * 64 + lane] = q8(v.x) | (q8(v.y) << 8) | (q8(v.z) << 16) | (q8(v.w) << 24);
    }
    for (int off = 32; off > 0; off >>= 1) s += __shfl_down(s, off, 64);
    if (lane == 0) {
        sq[row] = s;
        ap[row] = 0u;
        an[row] = 0x7F800000u;
    }
    if (threadIdx.x == 0 && blockIdx.x == 0) counter[0] = 0;
}

__global__ __launch_bounds__(256) void gemm_reduce_kernel(
    const unsigned char* __restrict__ xq,
    const float* __restrict__ sq,
    const int* __restrict__ labels,
    unsigned int* __restrict__ ap,
    unsigned int* __restrict__ an,
    int* __restrict__ counter,
    float* __restrict__ out) {
    __shared__ __align__(16) unsigned char As[64 * BK];    // 16 KB
    __shared__ __align__(16) unsigned char Bs[128 * BK];   // 32 KB

    const int orig = blockIdx.x;
    int g = (orig & 7) * (NTILES / 8) + (orig >> 3);
    int si = 0, row_cnt = 244;
    while (g >= row_cnt) { g -= row_cnt; ++si; row_cnt -= 32; }
    int mi64, nj;
    if (g < 20) {
        int ml = 0;
        while (g >= 4 - (ml >> 1)) { g -= 4 - (ml >> 1); ++ml; }
        mi64 = si * 8 + ml;
        nj = si * 4 + (ml >> 1) + g;
    } else {
        g -= 20;
        const int sj = si + 1 + (g >> 5);
        const int r = g & 31;
        mi64 = si * 8 + (r >> 2);
        nj = sj * 4 + (r & 3);
    }
    const int row0 = mi64 * 64;
    const int col0 = nj * 128;
    const int phase = orig & (NIT - 1);

    const int t = threadIdx.x;
    const int lane = t & 63;
    const int wave = t >> 6;
    const int c = lane & 15;
    const int q = lane >> 4;
    const int wc = wave * 32;

    i32x4 acc[4][2];
#pragma unroll
    for (int mi = 0; mi < 4; ++mi)
#pragma unroll
        for (int ni = 0; ni < 2; ++ni)
            acc[mi][ni] = (i32x4){0, 0, 0, 0};

    const int rowb = t >> 4;
    const int colsw = (t & 15) ^ (rowb & 15);
    const unsigned char* gA[4];
    const unsigned char* gB[8];
#pragma unroll
    for (int s = 0; s < 4; ++s)
        gA[s] = xq + (size_t)(row0 + rowb + 16 * s) * DD + colsw * 16;
#pragma unroll
    for (int s = 0; s < 8; ++s)
        gB[s] = xq + (size_t)(col0 + rowb + 16 * s) * DD + colsw * 16;

    for (int it = 0; it < NIT; ++it) {
        const int k0 = ((it + phase) & (NIT - 1)) * BK;
#pragma unroll
        for (int s = 0; s < 4; ++s)
            __builtin_amdgcn_global_load_lds(
                (const __attribute__((address_space(1))) void*)(gA[s] + k0),
                (__attribute__((address_space(3))) void*)&As[(t + 256 * s) * 16],
                16, 0, 0);
#pragma unroll
        for (int s = 0; s < 8; ++s)
            __builtin_amdgcn_global_load_lds(
                (const __attribute__((address_space(1))) void*)(gB[s] + k0),
                (__attribute__((address_space(3))) void*)&Bs[(t + 256 * s) * 16],
                16, 0, 0);
        __syncthreads();

        const i32x4* Av = (const i32x4*)As;
        const i32x4* Bv = (const i32x4*)Bs;
#pragma unroll
        for (int ks = 0; ks < 4; ++ks) {
            const int kc = q + 4 * ks;
            i32x4 af[4], bfr[2];
#pragma unroll
            for (int mi = 0; mi < 4; ++mi) {
                const int r = mi * 16 + c;
                af[mi] = Av[r * 16 + (kc ^ (r & 15))];
            }
#pragma unroll
            for (int ni = 0; ni < 2; ++ni) {
                const int r = wc + ni * 16 + c;
                bfr[ni] = Bv[r * 16 + (kc ^ (r & 15))];
            }
#pragma unroll
            for (int mi = 0; mi < 4; ++mi)
#pragma unroll
                for (int ni = 0; ni < 2; ++ni)
                    acc[mi][ni] = __builtin_amdgcn_mfma_i32_16x16x64_i8(
                        af[mi], bfr[ni], acc[mi][ni], 0, 0, 0);
        }
        __syncthreads();
    }

    float sq_col[2];
    int lab_col[2];
#pragma unroll
    for (int ni = 0; ni < 2; ++ni) {
        const int gj = col0 + wc + ni * 16 + c;
        sq_col[ni] = sq[gj];
        lab_col[ni] = labels[gj];
    }
    int lab_row[4][4];
    float dist[4][2][4];
#pragma unroll
    for (int mi = 0; mi < 4; ++mi) {
#pragma unroll
        for (int r = 0; r < 4; ++r) {
            const int gi = row0 + mi * 16 + q * 4 + r;
            const float sqi = sq[gi];
            lab_row[mi][r] = labels[gi];
#pragma unroll
            for (int ni = 0; ni < 2; ++ni) {
                float d2 = sqi + sq_col[ni] - C2 * (float)acc[mi][ni][r];
                dist[mi][ni][r] = sqrtf(fmaxf(d2, 0.0f));
            }
        }
    }
#pragma unroll
    for (int mi = 0; mi < 4; ++mi) {
#pragma unroll
        for (int r = 0; r < 4; ++r) {
            const int gi = row0 + mi * 16 + q * 4 + r;
            const int li = lab_row[mi][r];
            float apm = 0.0f;
            float anm = __builtin_inff();
#pragma unroll
            for (int ni = 0; ni < 2; ++ni) {
                const int gj = col0 + wc + ni * 16 + c;
                const float d = dist[mi][ni][r];
                if (li == lab_col[ni]) {
                    if (gi != gj) apm = fmaxf(apm, d);
                } else {
                    anm = fminf(anm, d);
                }
            }
#pragma unroll
            for (int off = 1; off < 16; off <<= 1) {
                apm = fmaxf(apm, __shfl_xor(apm, off, 16));
                anm = fminf(anm, __shfl_xor(anm, off, 16));
            }
            if (c == 0) {
                atomicMax(&ap[gi], __float_as_uint(apm));
                atomicMin(&an[gi], __float_as_uint(anm));
            }
        }
    }
#pragma unroll
    for (int ni = 0; ni < 2; ++ni) {
        const int gj = col0 + wc + ni * 16 + c;
        const int lj = lab_col[ni];
        float apm = 0.0f;
        float anm = __builtin_inff();
#pragma unroll
        for (int mi = 0; mi < 4; ++mi) {
#pragma unroll
            for (int r = 0; r < 4; ++r) {
                const int gi = row0 + mi * 16 + q * 4 + r;
                const float d = dist[mi][ni][r];
                if (lj == lab_row[mi][r]) {
                    if (gi != gj) apm = fmaxf(apm, d);
                } else {
                    anm = fminf(anm, d);
                }
            }
        }
        apm = fmaxf(apm, __shfl_xor(apm, 16, 64));
        anm = fminf(anm, __shfl_xor(anm, 16, 64));
        apm = fmaxf(apm, __shfl_xor(apm, 32, 64));
        anm = fminf(anm, __shfl_xor(anm, 32, 64));
        if (q == 0) {
            atomicMax(&ap[gj], __float_as_uint(apm));
            atomicMin(&an[gj], __float_as_uint(anm));
        }
    }

    __syncthreads();
    int* flag = (int*)As;
    if (t == 0) {
        int old = __hip_atomic_fetch_add(counter, 1, __ATOMIC_ACQ_REL,
                                         __HIP_MEMORY_SCOPE_AGENT);
        flag[0] = (old == NTILES - 1) ? 1 : 0;
    }
    __syncthreads();
    if (flag[0]) {
        float sum = 0.0f;
        int cnt = 0;
        for (int i = t; i < NN; i += 256) {
            const float a = __uint_as_float(__hip_atomic_load(
                &ap[i], __ATOMIC_RELAXED, __HIP_MEMORY_SCOPE_AGENT));
            const float b = __uint_as_float(__hip_atomic_load(
                &an[i], __ATOMIC_RELAXED, __HIP_MEMORY_SCOPE_AGENT));
            if ((a > 0.0f) && (b < __builtin_inff())) {
                sum += fmaxf(a - b + MARGIN_F, 0.0f);
                cnt += 1;
            }
        }
        for (int off = 32; off > 0; off >>= 1) {
            sum += __shfl_down(sum, off, 64);
            cnt += __shfl_down(cnt, off, 64);
        }
        float* ssum = (float*)Bs;
        int* scnt = (int*)Bs + 8;
        if (lane == 0) { ssum[wave] = sum; scnt[wave] = cnt; }
        __syncthreads();
        if (t == 0) {
            float s = 0.0f; int n = 0;
#pragma unroll
            for (int w = 0; w < 4; ++w) { s += ssum[w]; n += scnt[w]; }
            out[0] = (n > 0) ? s / (float)n : 0.0f;
        }
    }
}

extern "C" void kernel_launch(void* const* d_in, const int* in_sizes, int n_in,
                              void* d_out, int out_size, void* d_ws, size_t ws_size,
                              hipStream_t stream) {
    const float* x = (const float*)d_in[0];
    const int* labels = (const int*)d_in[1];
    float* out = (float*)d_out;

    char* ws = (char*)d_ws;
    unsigned char* xq = (unsigned char*)ws;                         // 4096*2048 B
    float* sq = (float*)(ws + (size_t)NN * DD);
    unsigned int* ap = (unsigned int*)(ws + (size_t)NN * DD + (size_t)NN * 4);
    unsigned int* an = (unsigned int*)(ws + (size_t)NN * DD + (size_t)NN * 8);
    int* counter = (int*)(ws + (size_t)NN * DD + (size_t)NN * 12);

    // Grid for the cooperative kernel: occupancy-validated co-residency,
    // rounded down to a multiple of 8 (preserves tid->XCD partition).
    static int nblk = -2;  // -2 = not queried yet
    if (nblk == -2) {
        int maxb = 0, ncu = 0;
        hipError_t e1 = hipOccupancyMaxActiveBlocksPerMultiprocessor(
            &maxb, fused_kernel, 256, 0);
        hipError_t e2 = hipDeviceGetAttribute(
            &ncu, hipDeviceAttributeMultiprocessorCount, 0);
        if (e1 == hipSuccess && e2 == hipSuccess && maxb > 0 && ncu > 0) {
            long g = (long)maxb * ncu;
            if (g > NTILES) g = NTILES;
            g -= g % 8;
            nblk = (g >= 8) ? (int)g : -1;
        } else {
            nblk = -1;  // fall back
        }
    }

    bool launched = false;
    if (nblk > 0) {
        void* args[] = {(void*)&x, (void*)&labels, (void*)&xq, (void*)&sq,
                        (void*)&ap, (void*)&an, (void*)&out};
        hipError_t e = hipLaunchCooperativeKernel(
            reinterpret_cast<void*>(fused_kernel), dim3(nblk), dim3(256),
            args, 0, stream);
        if (e == hipSuccess) {
            launched = true;
        } else {
            nblk = -1;  // stop retrying the cooperative path
        }
    }
    if (!launched) {
        prep_kernel<<<NN / 4, 256, 0, stream>>>(x, xq, sq, ap, an, counter);
        gemm_reduce_kernel<<<NTILES, 256, 0, stream>>>(xq, sq, labels, ap, an,
                                                       counter, out);
    }
}

// Round 14
// 136.691 us; speedup vs baseline: 1.5893x; 1.5893x over previous
//
#include <hip/hip_runtime.h>

#define NN 4096
#define DD 2048
#define MARGIN_F 0.3f
#define NTILES 1056  // 64x128 tiles covering the upper triangle (dupes OK)
#define BK 128       // K bytes per stage
#define NIT (DD / BK)  // 16
#define QS (127.0f / 6.0f)
#define C2 (2.0f * (6.0f / 127.0f) * (6.0f / 127.0f))  // 2/QS^2

typedef __attribute__((ext_vector_type(4))) int i32x4;

__device__ __forceinline__ unsigned q8(float v) {
    int i = __float2int_rn(v * QS);
    i = min(127, max(-127, i));
    return (unsigned)(i & 255);
}

// 1024 blocks x 4 waves; each wave quantizes one row (int8) + fp32
// sum-of-squares; init ap/an/counter.
__global__ __launch_bounds__(256) void prep_kernel(const float* __restrict__ x,
                                                   unsigned char* __restrict__ xq,
                                                   float* __restrict__ sq,
                                                   unsigned int* __restrict__ ap,
                                                   unsigned int* __restrict__ an,
                                                   int* __restrict__ counter) {
    const int wave = threadIdx.x >> 6, lane = threadIdx.x & 63;
    const int row = blockIdx.x * 4 + wave;
    const float* xr = x + (size_t)row * DD;
    unsigned int* orow = (unsigned int*)(xq + (size_t)row * DD);
    float s = 0.0f;
#pragma unroll
    for (int j = 0; j < 8; ++j) {
        float4 v = ((const float4*)xr)[j * 64 + lane];
        s += v.x * v.x + v.y * v.y + v.z * v.z + v.w * v.w;
        orow[j * 64 + lane] = q8(v.x) | (q8(v.y) << 8) | (q8(v.z) << 16) | (q8(v.w) << 24);
    }
    for (int off = 32; off > 0; off >>= 1) s += __shfl_down(s, off, 64);
    if (lane == 0) {
        sq[row] = s;
        ap[row] = 0u;            // hardest-positive max starts at 0
        an[row] = 0x7F800000u;   // +inf
    }
    if (threadIdx.x == 0 && blockIdx.x == 0) counter[0] = 0;
}

// Symmetric batch-hard GEMM, int8. R14 = restore of R10, the session
// champion (measured: 135.8 us total, 64.2 us gemm, FETCH 23.2 MB).
// R13 post-mortem: cooperative fusion regressed (+90 us: grid.sync
// software barrier + L2 flush + lost dispatch pipelining) -> the
// residual is prep (~10 us, roofline-bound) + fixed harness cost, not
// launch overhead. R10's gemm runs AT the measured staging ceiling:
// 405 MB / 64 us = 6.33 TB/s = m13's achievable 6.29 TB/s. Structure:
// super-block L2 locality (512x512 supers, XCD x = orig&7 owns
// contiguous [132x,132x+132) -> footprint 2-3 MB < 4 MB L2; FETCH
// 38->23 MB) + counted-vmcnt double-buffer (BK=128, NIT=16, 48 KB LDS
// -> 3 blocks/CU; stage 2 ahead, vmcnt(6) per phase, never 0 in-loop)
// + XCD-uniform K-stagger phase=(orig&7)*2 (256-B granule).
// 8-chunk rows use col' = col ^ (row&7) swizzle (conflict-free, PMC=0).
// mfma_i32_16x16x64_i8, wave = 64 rows x 32 cols (4x2 frags). Both-side
// epilogues (idempotent max/min, gi!=gj guards diagonal); fused
// last-block finalize.
__global__ __launch_bounds__(256) void gemm_reduce_kernel(
    const unsigned char* __restrict__ xq,
    const float* __restrict__ sq,
    const int* __restrict__ labels,
    unsigned int* __restrict__ ap,
    unsigned int* __restrict__ an,
    int* __restrict__ counter,
    float* __restrict__ out) {
    __shared__ __align__(16) unsigned char As0[64 * BK];    // 8 KB
    __shared__ __align__(16) unsigned char Bs0[128 * BK];   // 16 KB
    __shared__ __align__(16) unsigned char As1[64 * BK];    // 8 KB
    __shared__ __align__(16) unsigned char Bs1[128 * BK];   // 16 KB

    // ---- super-block tile decode (R9 verbatim) ----
    // g = position in super-order; XCD (orig&7) owns run [132x, 132x+132).
    const int orig = blockIdx.x;
    int g = (orig & 7) * (NTILES / 8) + (orig >> 3);
    // super row si: row si holds 244 - 32*si tiles (diag 20 + (7-si)*32).
    int si = 0, row_cnt = 244;
    while (g >= row_cnt) { g -= row_cnt; ++si; row_cnt -= 32; }
    int mi64, nj;
    if (g < 20) {  // diagonal super (si,si): 8 row-tiles x 4 col-tiles tri
        int ml = 0;
        while (g >= 4 - (ml >> 1)) { g -= 4 - (ml >> 1); ++ml; }
        mi64 = si * 8 + ml;
        nj = si * 4 + (ml >> 1) + g;
    } else {       // off-diagonal super (si, sj): full 8x4
        g -= 20;
        const int sj = si + 1 + (g >> 5);
        const int r = g & 31;
        mi64 = si * 8 + (r >> 2);
        nj = sj * 4 + (r & 3);
    }
    const int row0 = mi64 * 64;
    const int col0 = nj * 128;
    const int phase = (orig & 7) * 2;  // XCD-uniform stagger, 256-B granule

    const int t = threadIdx.x;
    const int lane = t & 63;
    const int wave = t >> 6;
    const int c = lane & 15;   // fragment column lane
    const int q = lane >> 4;   // k-quad
    const int wc = wave * 32;  // wave col offset (rows shared by all waves)

    i32x4 acc[4][2];
#pragma unroll
    for (int mi = 0; mi < 4; ++mi)
#pragma unroll
        for (int ni = 0; ni < 2; ++ni)
            acc[mi][ni] = (i32x4){0, 0, 0, 0};

    // Staging: rows are 128 B = 8 chunks of 16 B. A tile 64 rows = 512
    // chunks (2/thread), B tile 128 rows = 1024 chunks (4/thread).
    // Chunk ci = t + 256*s: row = ci>>3 = (t>>3) + 32*s, col = t&7;
    // source col XOR-swizzled: col ^ (row&7), and row&7 = (t>>3)&7 is
    // s-invariant, so one swizzled col per thread.
    const int rowb = t >> 3;
    const int colsw = (t & 7) ^ (rowb & 7);
    const unsigned char* gA[2];
    const unsigned char* gB[4];
#pragma unroll
    for (int s = 0; s < 2; ++s)
        gA[s] = xq + (size_t)(row0 + rowb + 32 * s) * DD + colsw * 16;
#pragma unroll
    for (int s = 0; s < 4; ++s)
        gB[s] = xq + (size_t)(col0 + rowb + 32 * s) * DD + colsw * 16;

    // 6 global_load_lds per thread per stage (per-wave vmcnt += 6).
    auto stage = [&](unsigned char* A, unsigned char* B, int it) {
        const int k0 = ((it + phase) & (NIT - 1)) * BK;
#pragma unroll
        for (int s = 0; s < 2; ++s)
            __builtin_amdgcn_global_load_lds(
                (const __attribute__((address_space(1))) void*)(gA[s] + k0),
                (__attribute__((address_space(3))) void*)&A[(t + 256 * s) * 16],
                16, 0, 0);
#pragma unroll
        for (int s = 0; s < 4; ++s)
            __builtin_amdgcn_global_load_lds(
                (const __attribute__((address_space(1))) void*)(gB[s] + k0),
                (__attribute__((address_space(3))) void*)&B[(t + 256 * s) * 16],
                16, 0, 0);
    };

    auto compute = [&](const unsigned char* A, const unsigned char* B) {
        const i32x4* Av = (const i32x4*)A;
        const i32x4* Bv = (const i32x4*)B;
#pragma unroll
        for (int ks = 0; ks < 2; ++ks) {
            const int kc = q + 4 * ks;  // k-chunk for this lane's fragment
            i32x4 af[4], bfr[2];
#pragma unroll
            for (int mi = 0; mi < 4; ++mi) {
                const int r = mi * 16 + c;
                af[mi] = Av[r * 8 + (kc ^ (r & 7))];
            }
#pragma unroll
            for (int ni = 0; ni < 2; ++ni) {
                const int r = wc + ni * 16 + c;
                bfr[ni] = Bv[r * 8 + (kc ^ (r & 7))];
            }
#pragma unroll
            for (int mi = 0; mi < 4; ++mi)
#pragma unroll
                for (int ni = 0; ni < 2; ++ni)
                    acc[mi][ni] = __builtin_amdgcn_mfma_i32_16x16x64_i8(
                        af[mi], bfr[ni], acc[mi][ni], 0, 0, 0);
        }
    };

    // Counted-vmcnt pipeline (R2 verbatim). Ledger (per wave, 6/stage):
    //   prologue: stage(0), stage(1)            -> 12 outstanding
    //   phase(it): vmcnt(6) waits stage(it) done (only stage(it+1)'s 6
    //   remain); s_barrier -> buf ready all waves; compute; fence +
    //   s_barrier -> all waves done READING buf; re-stage buf for it+2.
    //   Last phase vmcnt(0) (nothing behind it). No drain elsewhere.
    stage(As0, Bs0, 0);
    stage(As1, Bs1, 1);
#pragma unroll
    for (int it = 0; it < NIT; it += 2) {
        // ---- phase A: tile it in {As0,Bs0} ----
        asm volatile("s_waitcnt vmcnt(6)" ::: "memory");
        __builtin_amdgcn_s_barrier();
        compute(As0, Bs0);
        asm volatile("" ::: "memory");  // keep ds_reads above the barrier
        __builtin_amdgcn_s_barrier();
        if (it + 2 < NIT) stage(As0, Bs0, it + 2);
        // ---- phase B: tile it+1 in {As1,Bs1} ----
        if (it + 2 < NIT)
            asm volatile("s_waitcnt vmcnt(6)" ::: "memory");
        else
            asm volatile("s_waitcnt vmcnt(0)" ::: "memory");
        __builtin_amdgcn_s_barrier();
        compute(As1, Bs1);
        asm volatile("" ::: "memory");
        __builtin_amdgcn_s_barrier();
        if (it + 3 < NIT) stage(As1, Bs1, it + 3);
    }

    // --- Epilogue ---
    // C/D layout 16x16: col = lane&15 (c), row = q*4 + reg [m89/m91;
    // dtype-independent m121-m128]
    float sq_col[2];
    int lab_col[2];
#pragma unroll
    for (int ni = 0; ni < 2; ++ni) {
        const int gj = col0 + wc + ni * 16 + c;
        sq_col[ni] = sq[gj];
        lab_col[ni] = labels[gj];
    }
    int lab_row[4][4];
    float dist[4][2][4];
#pragma unroll
    for (int mi = 0; mi < 4; ++mi) {
#pragma unroll
        for (int r = 0; r < 4; ++r) {
            const int gi = row0 + mi * 16 + q * 4 + r;
            const float sqi = sq[gi];
            lab_row[mi][r] = labels[gi];
#pragma unroll
            for (int ni = 0; ni < 2; ++ni) {
                float d2 = sqi + sq_col[ni] - C2 * (float)acc[mi][ni][r];
                dist[mi][ni][r] = sqrtf(fmaxf(d2, 0.0f));
            }
        }
    }

    // Row-side: rows gi vs this wave's 32 columns.
#pragma unroll
    for (int mi = 0; mi < 4; ++mi) {
#pragma unroll
        for (int r = 0; r < 4; ++r) {
            const int gi = row0 + mi * 16 + q * 4 + r;
            const int li = lab_row[mi][r];
            float apm = 0.0f;
            float anm = __builtin_inff();
#pragma unroll
            for (int ni = 0; ni < 2; ++ni) {
                const int gj = col0 + wc + ni * 16 + c;
                const float d = dist[mi][ni][r];
                if (li == lab_col[ni]) {
                    if (gi != gj) apm = fmaxf(apm, d);  // exclude diagonal
                } else {
                    anm = fminf(anm, d);
                }
            }
#pragma unroll
            for (int off = 1; off < 16; off <<= 1) {
                apm = fmaxf(apm, __shfl_xor(apm, off, 16));
                anm = fminf(anm, __shfl_xor(anm, off, 16));
            }
            if (c == 0) {
                atomicMax(&ap[gi], __float_as_uint(apm));
                atomicMin(&an[gi], __float_as_uint(anm));
            }
        }
    }

    // Column-side (transposed): S(gi,gj) also serves row gj (dupes
    // idempotent; diagonal guarded).
#pragma unroll
    for (int ni = 0; ni < 2; ++ni) {
        const int gj = col0 + wc + ni * 16 + c;
        const int lj = lab_col[ni];
        float apm = 0.0f;
        float anm = __builtin_inff();
#pragma unroll
        for (int mi = 0; mi < 4; ++mi) {
#pragma unroll
            for (int r = 0; r < 4; ++r) {
                const int gi = row0 + mi * 16 + q * 4 + r;
                const float d = dist[mi][ni][r];
                if (lj == lab_row[mi][r]) {
                    if (gi != gj) apm = fmaxf(apm, d);  // exclude diagonal
                } else {
                    anm = fminf(anm, d);
                }
            }
        }
        apm = fmaxf(apm, __shfl_xor(apm, 16, 64));
        anm = fminf(anm, __shfl_xor(anm, 16, 64));
        apm = fmaxf(apm, __shfl_xor(apm, 32, 64));
        anm = fminf(anm, __shfl_xor(anm, 32, 64));
        if (q == 0) {
            atomicMax(&ap[gj], __float_as_uint(apm));
            atomicMin(&an[gj], __float_as_uint(anm));
        }
    }

    // --- Fused finalize: last block to finish reduces the loss ---
    __syncthreads();  // drains this block's atomics before counter release
    int* flag = (int*)As0;
    if (t == 0) {
        int old = __hip_atomic_fetch_add(counter, 1, __ATOMIC_ACQ_REL,
                                         __HIP_MEMORY_SCOPE_AGENT);
        flag[0] = (old == NTILES - 1) ? 1 : 0;
    }
    __syncthreads();
    if (flag[0]) {
        float sum = 0.0f;
        int cnt = 0;
        for (int i = t; i < NN; i += 256) {
            const float a = __uint_as_float(__hip_atomic_load(
                &ap[i], __ATOMIC_RELAXED, __HIP_MEMORY_SCOPE_AGENT));
            const float b = __uint_as_float(__hip_atomic_load(
                &an[i], __ATOMIC_RELAXED, __HIP_MEMORY_SCOPE_AGENT));
            if ((a > 0.0f) && (b < __builtin_inff())) {
                sum += fmaxf(a - b + MARGIN_F, 0.0f);
                cnt += 1;
            }
        }
        for (int off = 32; off > 0; off >>= 1) {
            sum += __shfl_down(sum, off, 64);
            cnt += __shfl_down(cnt, off, 64);
        }
        float* ssum = (float*)Bs0;
        int* scnt = (int*)Bs0 + 8;
        if (lane == 0) { ssum[wave] = sum; scnt[wave] = cnt; }
        __syncthreads();
        if (t == 0) {
            float s = 0.0f; int n = 0;
#pragma unroll
            for (int w = 0; w < 4; ++w) { s += ssum[w]; n += scnt[w]; }
            out[0] = (n > 0) ? s / (float)n : 0.0f;
        }
    }
}

extern "C" void kernel_launch(void* const* d_in, const int* in_sizes, int n_in,
                              void* d_out, int out_size, void* d_ws, size_t ws_size,
                              hipStream_t stream) {
    const float* x = (const float*)d_in[0];
    const int* labels = (const int*)d_in[1];
    float* out = (float*)d_out;

    char* ws = (char*)d_ws;
    unsigned char* xq = (unsigned char*)ws;                         // 4096*2048 B
    float* sq = (float*)(ws + (size_t)NN * DD);
    unsigned int* ap = (unsigned int*)(ws + (size_t)NN * DD + (size_t)NN * 4);
    unsigned int* an = (unsigned int*)(ws + (size_t)NN * DD + (size_t)NN * 8);
    int* counter = (int*)(ws + (size_t)NN * DD + (size_t)NN * 12);

    prep_kernel<<<NN / 4, 256, 0, stream>>>(x, xq, sq, ap, an, counter);
    gemm_reduce_kernel<<<NTILES, 256, 0, stream>>>(xq, sq, labels, ap, an, counter, out);
}

// Round 15
// 130.648 us; speedup vs baseline: 1.6628x; 1.0463x over previous
//
#include <hip/hip_runtime.h>

#define NN 4096
#define DD 2048
#define MARGIN_F 0.3f
#define NTILES 528   // 128x128 tiles covering the upper triangle (nj >= mi)
#define BK 128       // K bytes per stage
#define NIT (DD / BK)  // 16
#define QS (127.0f / 6.0f)
#define C2 (2.0f * (6.0f / 127.0f) * (6.0f / 127.0f))  // 2/QS^2

typedef __attribute__((ext_vector_type(4))) int i32x4;

__device__ __forceinline__ unsigned q8(float v) {
    int i = __float2int_rn(v * QS);
    i = min(127, max(-127, i));
    return (unsigned)(i & 255);
}

// 1024 blocks x 4 waves; each wave quantizes one row (int8) + fp32
// sum-of-squares; init ap/an/counter.
__global__ __launch_bounds__(256) void prep_kernel(const float* __restrict__ x,
                                                   unsigned char* __restrict__ xq,
                                                   float* __restrict__ sq,
                                                   unsigned int* __restrict__ ap,
                                                   unsigned int* __restrict__ an,
                                                   int* __restrict__ counter) {
    const int wave = threadIdx.x >> 6, lane = threadIdx.x & 63;
    const int row = blockIdx.x * 4 + wave;
    const float* xr = x + (size_t)row * DD;
    unsigned int* orow = (unsigned int*)(xq + (size_t)row * DD);
    float s = 0.0f;
#pragma unroll
    for (int j = 0; j < 8; ++j) {
        float4 v = ((const float4*)xr)[j * 64 + lane];
        s += v.x * v.x + v.y * v.y + v.z * v.z + v.w * v.w;
        orow[j * 64 + lane] = q8(v.x) | (q8(v.y) << 8) | (q8(v.z) << 16) | (q8(v.w) << 24);
    }
    for (int off = 32; off > 0; off >>= 1) s += __shfl_down(s, off, 64);
    if (lane == 0) {
        sq[row] = s;
        ap[row] = 0u;            // hardest-positive max starts at 0
        an[row] = 0x7F800000u;   // +inf
    }
    if (threadIdx.x == 0 && blockIdx.x == 0) counter[0] = 0;
}

// Symmetric batch-hard GEMM, int8. R15: the last untested matrix cell —
// 128x128 tiles (staged bytes 405->276 MB) with NONE of the prior 128^2
// failure modes: R8 lacked locality (FETCH 57.8 MB); R11 had locality
// but 2 blocks/CU + 512-wide barriers (rate 6.1 B/cyc). Here: 256 thr /
// 4 waves, BK=128 SINGLE-buffer = 32 KB LDS -> 3 blocks/CU (launch_
// bounds(256,3) caps VGPR for 3 waves/SIMD) -> ALL 528 blocks
// co-resident; R11's super-block locality decode (verified: FETCH
// 22.4 MB); XCD-uniform K-stagger phase=(orig&7)*2; plain drain
// barriers (R9 regime, 10.4 B/cyc at 3/CU). Wave = 128 rows x 32 cols
// (8x2 frags, acc 64 VGPR), 32 MFMA + 8 gload_lds per thread per iter.
// 8-chunk rows use col' = col ^ (row&7) swizzle (conflict-free, PMC=0).
// Both-side epilogues (idempotent max/min, gi!=gj guards diagonal);
// fused last-block finalize.
__global__ __launch_bounds__(256, 3) void gemm_reduce_kernel(
    const unsigned char* __restrict__ xq,
    const float* __restrict__ sq,
    const int* __restrict__ labels,
    unsigned int* __restrict__ ap,
    unsigned int* __restrict__ an,
    int* __restrict__ counter,
    float* __restrict__ out) {
    __shared__ __align__(16) unsigned char As[128 * BK];   // 16 KB
    __shared__ __align__(16) unsigned char Bs[128 * BK];   // 16 KB

    // ---- super-block tile decode (R11 verbatim; 4x4-tile supers) ----
    // g = position in super-order; XCD (orig&7) owns run [66x, 66x+66).
    const int orig = blockIdx.x;
    int g = (orig & 7) * (NTILES / 8) + (orig >> 3);
    // super row si holds 10 (diag) + (7-si)*16 tiles.
    int si = 0, row_cnt = 122;  // 10 + 7*16
    while (g >= row_cnt) { g -= row_cnt; ++si; row_cnt -= 16; }
    int mi_t, nj;
    if (g < 10) {  // diagonal super (si,si): 4x4 triangle, nj >= mi
        int ml = 0;
        while (g >= 4 - ml) { g -= 4 - ml; ++ml; }
        mi_t = si * 4 + ml;
        nj = si * 4 + ml + g;
    } else {       // off-diagonal super (si, sj): full 4x4
        g -= 10;
        const int sj = si + 1 + (g >> 4);
        const int r = g & 15;
        mi_t = si * 4 + (r >> 2);
        nj = sj * 4 + (r & 3);
    }
    const int row0 = mi_t * 128;
    const int col0 = nj * 128;
    const int phase = (orig & 7) * 2;  // XCD-uniform stagger, 256-B granule

    const int t = threadIdx.x;
    const int lane = t & 63;
    const int wave = t >> 6;
    const int c = lane & 15;   // fragment column lane
    const int q = lane >> 4;   // k-quad
    const int wc = wave * 32;  // wave col offset (all 128 rows per wave)

    i32x4 acc[8][2];
#pragma unroll
    for (int mi = 0; mi < 8; ++mi)
#pragma unroll
        for (int ni = 0; ni < 2; ++ni)
            acc[mi][ni] = (i32x4){0, 0, 0, 0};

    // Staging: rows are 128 B = 8 chunks of 16 B. Each tile (A or B) is
    // 128 rows = 1024 chunks; 256 threads -> 4 chunks/thread/tile.
    // Chunk ci = t + 256*s: row = ci>>3 = (t>>3) + 32*s, col = t&7;
    // source col XOR-swizzled: col ^ (row&7); row&7 = (t>>3)&7 is
    // s-invariant, so one swizzled col per thread.
    const int rowb = t >> 3;
    const int colsw = (t & 7) ^ (rowb & 7);
    const unsigned char* gA[4];
    const unsigned char* gB[4];
#pragma unroll
    for (int s = 0; s < 4; ++s) {
        gA[s] = xq + (size_t)(row0 + rowb + 32 * s) * DD + colsw * 16;
        gB[s] = xq + (size_t)(col0 + rowb + 32 * s) * DD + colsw * 16;
    }

    for (int it = 0; it < NIT; ++it) {
        const int k0 = ((it + phase) & (NIT - 1)) * BK;
#pragma unroll
        for (int s = 0; s < 4; ++s)
            __builtin_amdgcn_global_load_lds(
                (const __attribute__((address_space(1))) void*)(gA[s] + k0),
                (__attribute__((address_space(3))) void*)&As[(t + 256 * s) * 16],
                16, 0, 0);
#pragma unroll
        for (int s = 0; s < 4; ++s)
            __builtin_amdgcn_global_load_lds(
                (const __attribute__((address_space(1))) void*)(gB[s] + k0),
                (__attribute__((address_space(3))) void*)&Bs[(t + 256 * s) * 16],
                16, 0, 0);
        __syncthreads();

        const i32x4* Av = (const i32x4*)As;
        const i32x4* Bv = (const i32x4*)Bs;
#pragma unroll
        for (int ks = 0; ks < 2; ++ks) {
            const int kc = q + 4 * ks;  // k-chunk for this lane's fragment
            i32x4 bfr[2];
#pragma unroll
            for (int ni = 0; ni < 2; ++ni) {
                const int r = wc + ni * 16 + c;
                bfr[ni] = Bv[r * 8 + (kc ^ (r & 7))];
            }
#pragma unroll
            for (int mi = 0; mi < 8; ++mi) {
                const int r = mi * 16 + c;
                const i32x4 af = Av[r * 8 + (kc ^ (r & 7))];
#pragma unroll
                for (int ni = 0; ni < 2; ++ni)
                    acc[mi][ni] = __builtin_amdgcn_mfma_i32_16x16x64_i8(
                        af, bfr[ni], acc[mi][ni], 0, 0, 0);
            }
        }
        __syncthreads();
    }

    // --- Epilogue ---
    // C/D layout 16x16: col = lane&15 (c), row = q*4 + reg [m89/m91;
    // dtype-independent m121-m128]
    float sq_col[2];
    int lab_col[2];
#pragma unroll
    for (int ni = 0; ni < 2; ++ni) {
        const int gj = col0 + wc + ni * 16 + c;
        sq_col[ni] = sq[gj];
        lab_col[ni] = labels[gj];
    }
    int lab_row[8][4];
    float dist[8][2][4];
#pragma unroll
    for (int mi = 0; mi < 8; ++mi) {
#pragma unroll
        for (int r = 0; r < 4; ++r) {
            const int gi = row0 + mi * 16 + q * 4 + r;
            const float sqi = sq[gi];
            lab_row[mi][r] = labels[gi];
#pragma unroll
            for (int ni = 0; ni < 2; ++ni) {
                float d2 = sqi + sq_col[ni] - C2 * (float)acc[mi][ni][r];
                dist[mi][ni][r] = sqrtf(fmaxf(d2, 0.0f));
            }
        }
    }

    // Row-side: rows gi vs this wave's 32 columns.
#pragma unroll
    for (int mi = 0; mi < 8; ++mi) {
#pragma unroll
        for (int r = 0; r < 4; ++r) {
            const int gi = row0 + mi * 16 + q * 4 + r;
            const int li = lab_row[mi][r];
            float apm = 0.0f;
            float anm = __builtin_inff();
#pragma unroll
            for (int ni = 0; ni < 2; ++ni) {
                const int gj = col0 + wc + ni * 16 + c;
                const float d = dist[mi][ni][r];
                if (li == lab_col[ni]) {
                    if (gi != gj) apm = fmaxf(apm, d);  // exclude diagonal
                } else {
                    anm = fminf(anm, d);
                }
            }
#pragma unroll
            for (int off = 1; off < 16; off <<= 1) {
                apm = fmaxf(apm, __shfl_xor(apm, off, 16));
                anm = fminf(anm, __shfl_xor(anm, off, 16));
            }
            if (c == 0) {
                atomicMax(&ap[gi], __float_as_uint(apm));
                atomicMin(&an[gi], __float_as_uint(anm));
            }
        }
    }

    // Column-side (transposed): S(gi,gj) also serves row gj (dupes
    // idempotent; diagonal guarded).
#pragma unroll
    for (int ni = 0; ni < 2; ++ni) {
        const int gj = col0 + wc + ni * 16 + c;
        const int lj = lab_col[ni];
        float apm = 0.0f;
        float anm = __builtin_inff();
#pragma unroll
        for (int mi = 0; mi < 8; ++mi) {
#pragma unroll
            for (int r = 0; r < 4; ++r) {
                const int gi = row0 + mi * 16 + q * 4 + r;
                const float d = dist[mi][ni][r];
                if (lj == lab_row[mi][r]) {
                    if (gi != gj) apm = fmaxf(apm, d);  // exclude diagonal
                } else {
                    anm = fminf(anm, d);
                }
            }
        }
        apm = fmaxf(apm, __shfl_xor(apm, 16, 64));
        anm = fminf(anm, __shfl_xor(anm, 16, 64));
        apm = fmaxf(apm, __shfl_xor(apm, 32, 64));
        anm = fminf(anm, __shfl_xor(anm, 32, 64));
        if (q == 0) {
            atomicMax(&ap[gj], __float_as_uint(apm));
            atomicMin(&an[gj], __float_as_uint(anm));
        }
    }

    // --- Fused finalize: last block to finish reduces the loss ---
    __syncthreads();  // drains this block's atomics before counter release
    int* flag = (int*)As;
    if (t == 0) {
        int old = __hip_atomic_fetch_add(counter, 1, __ATOMIC_ACQ_REL,
                                         __HIP_MEMORY_SCOPE_AGENT);
        flag[0] = (old == NTILES - 1) ? 1 : 0;
    }
    __syncthreads();
    if (flag[0]) {
        float sum = 0.0f;
        int cnt = 0;
        for (int i = t; i < NN; i += 256) {
            const float a = __uint_as_float(__hip_atomic_load(
                &ap[i], __ATOMIC_RELAXED, __HIP_MEMORY_SCOPE_AGENT));
            const float b = __uint_as_float(__hip_atomic_load(
                &an[i], __ATOMIC_RELAXED, __HIP_MEMORY_SCOPE_AGENT));
            if ((a > 0.0f) && (b < __builtin_inff())) {
                sum += fmaxf(a - b + MARGIN_F, 0.0f);
                cnt += 1;
            }
        }
        for (int off = 32; off > 0; off >>= 1) {
            sum += __shfl_down(sum, off, 64);
            cnt += __shfl_down(cnt, off, 64);
        }
        float* ssum = (float*)Bs;
        int* scnt = (int*)Bs + 8;
        if (lane == 0) { ssum[wave] = sum; scnt[wave] = cnt; }
        __syncthreads();
        if (t == 0) {
            float s = 0.0f; int n = 0;
#pragma unroll
            for (int w = 0; w < 4; ++w) { s += ssum[w]; n += scnt[w]; }
            out[0] = (n > 0) ? s / (float)n : 0.0f;
        }
    }
}

extern "C" void kernel_launch(void* const* d_in, const int* in_sizes, int n_in,
                              void* d_out, int out_size, void* d_ws, size_t ws_size,
                              hipStream_t stream) {
    const float* x = (const float*)d_in[0];
    const int* labels = (const int*)d_in[1];
    float* out = (float*)d_out;

    char* ws = (char*)d_ws;
    unsigned char* xq = (unsigned char*)ws;                         // 4096*2048 B
    float* sq = (float*)(ws + (size_t)NN * DD);
    unsigned int* ap = (unsigned int*)(ws + (size_t)NN * DD + (size_t)NN * 4);
    unsigned int* an = (unsigned int*)(ws + (size_t)NN * DD + (size_t)NN * 8);
    int* counter = (int*)(ws + (size_t)NN * DD + (size_t)NN * 12);

    prep_kernel<<<NN / 4, 256, 0, stream>>>(x, xq, sq, ap, an, counter);
    gemm_reduce_kernel<<<NTILES, 256, 0, stream>>>(xq, sq, labels, ap, an, counter, out);
}